// Round 19
// baseline (223.611 us; speedup 1.0000x reference)
//
#include <hip/hip_runtime.h>
#include <hip/hip_bf16.h>

#define DD 128
#define NBKMAX 512
#define FMAX 4096

typedef __attribute__((ext_vector_type(8))) short bf16x8;
typedef __attribute__((ext_vector_type(8))) unsigned short u16x8;
typedef __attribute__((ext_vector_type(4))) float f32x4;

__device__ __forceinline__ float b2f(unsigned short u){
  return __uint_as_float((unsigned int)u << 16);
}
__device__ __forceinline__ unsigned short f2b(float f){
  unsigned int u = __float_as_uint(f);
  unsigned int r = (u + 0x7FFFu + ((u >> 16) & 1u)) >> 16;   // RNE
  return (unsigned short)r;
}

// ---------------- fused: max-depth reduction + x -> bf16 cast ----------------
__global__ void k_dc(const int* __restrict__ depths, int* __restrict__ maxd,
                     const float* __restrict__ x, unsigned short* __restrict__ xb,
                     int n, int total4){
  int tid = blockIdx.x * blockDim.x + threadIdx.x;
  int stride = gridDim.x * blockDim.x;
  int v = 0;
  for (int i = tid; i < n; i += stride){
    int d = depths[i]; v = d > v ? d : v;
  }
  #pragma unroll
  for (int off = 32; off; off >>= 1){ int o = __shfl_xor(v, off); v = o > v ? o : v; }
  if ((threadIdx.x & 63) == 0) atomicMax(maxd, v);
  for (int i = tid; i < total4; i += stride){
    float4 vv = ((const float4*)x)[i];
    ushort4 w;
    w.x = f2b(vv.x); w.y = f2b(vv.y); w.z = f2b(vv.z); w.w = f2b(vv.w);
    ((ushort4*)xb)[i] = w;
  }
}

// ---------------- gate MLP: scale_weights (sw[3]), init lc = ba ----------------
__global__ void k_gate(const int* __restrict__ maxd, const float* __restrict__ Wg1,
                       const float* __restrict__ bg1, const float* __restrict__ Wg2,
                       const float* __restrict__ bg2, const float* __restrict__ ba,
                       float* __restrict__ sw, float* __restrict__ lc, float sf0){
  __shared__ float h[32];
  int t = threadIdx.x;
  float sf1 = (float)(*maxd) / 20.0f;
  if (t < 32) h[t] = fmaxf(0.0f, sf0 * Wg1[t] + sf1 * Wg1[32 + t] + bg1[t]);
  __syncthreads();
  if (t < 3){
    float s = bg2[t];
    for (int k = 0; k < 32; ++k) s += h[k] * Wg2[k * 3 + t];
    sw[t] = 1.0f / (1.0f + __expf(-s));
    lc[t] = ba[t];
  }
}

// ---------------- combined matrices: Vt (bf16, B-fragment order) and ob ----------------
__global__ void k_combine(const float* __restrict__ Wh, const float* __restrict__ bh,
                          const float* __restrict__ Wf, const float* __restrict__ sw,
                          unsigned short* __restrict__ Vt, float* __restrict__ ob){
  int k = blockIdx.x;        // 0..128 (128 == bias row)
  int i = blockIdx.y;        // hop
  int c = threadIdx.x;       // col 0..127
  float s = sw[i];
  float acc = 0.0f;
  if (k < DD){
    for (int d = 0; d < DD; ++d)
      acc += Wh[(i * DD + k) * DD + d] * Wf[(i * DD + d) * DD + c];
    int ktt = i * 4 + (k >> 5);
    int g = (k >> 3) & 3;
    int j = k & 7;
    Vt[((((size_t)ktt * DD + c) * 4 + g) << 3) + j] = f2b(s * acc);
  } else {
    for (int d = 0; d < DD; ++d)
      acc += bh[i * DD + d] * Wf[(i * DD + d) * DD + c];
    ob[i * DD + c] = s * acc;
  }
}

// ---------------- U (transposed): U[(i*3+j)*DD + k] = sw_i * sum_d Wh_i[k][d] Wa_i[d][j];
//                  lc += sw_i * bh_i @ Wa_i ----------------
__global__ void k_ua(const float* __restrict__ Wh, const float* __restrict__ bh,
                     const float* __restrict__ Wa, const float* __restrict__ sw,
                     float* __restrict__ U, float* __restrict__ lc){
  int i = blockIdx.x, k = threadIdx.x;
  float s = sw[i];
  float a0 = 0, a1 = 0, a2 = 0;
  for (int d = 0; d < DD; ++d){
    float w = Wh[(i * DD + k) * DD + d];
    a0 += w * Wa[(i * DD + d) * 3 + 0];
    a1 += w * Wa[(i * DD + d) * 3 + 1];
    a2 += w * Wa[(i * DD + d) * 3 + 2];
  }
  U[(i * 3 + 0) * DD + k] = s * a0;
  U[(i * 3 + 1) * DD + k] = s * a1;
  U[(i * 3 + 2) * DD + k] = s * a2;
  if (k < 3){
    float b = 0;
    for (int d = 0; d < DD; ++d) b += bh[i * DD + d] * Wa[(i * DD + d) * 3 + k];
    atomicAdd(&lc[k], s * b);
  }
}

// ---------------- CSR build (fast path, N<65536): bucket histogram only ----------------
__global__ void k_histb(const int* __restrict__ col, int* __restrict__ bcnt, int e){
  __shared__ int lb[NBKMAX];
  int t = threadIdx.x;
  for (int q = t; q < NBKMAX; q += 256) lb[q] = 0;
  __syncthreads();
  for (int i = blockIdx.x * blockDim.x + t; i < e; i += gridDim.x * blockDim.x)
    atomicAdd(&lb[col[i] >> 7], 1);
  __syncthreads();
  for (int q = t; q < NBKMAX; q += 256)
    if (lb[q] > 0) atomicAdd(&bcnt[q], lb[q]);
}

__global__ void k_bscan(const int* __restrict__ bcnt, int* __restrict__ bkb,
                        int* __restrict__ bcur, int nbk){
  int lane = threadIdx.x & 63;
  int carry = 0;
  for (int s = 0; s < nbk; s += 64){
    int idx = s + lane;
    int v = (idx < nbk) ? bcnt[idx] : 0;
    int incl = v;
    #pragma unroll
    for (int d = 1; d < 64; d <<= 1){
      int o = __shfl_up(incl, d);
      if (lane >= d) incl += o;
    }
    if (idx < nbk){ int ex = carry + incl - v; bkb[idx] = ex; bcur[idx] = ex; }
    carry += __shfl(incl, 63);
  }
}

__global__ void k_part(const int* __restrict__ row, const int* __restrict__ col,
                       int* __restrict__ bcur, unsigned int* __restrict__ bkt, int e){
  __shared__ int lh[NBKMAX];
  __shared__ int lbase[NBKMAX];
  int t = threadIdx.x;
  int start = blockIdx.x * 8192;
  int end = start + 8192; if (end > e) end = e;
  for (int q = t; q < NBKMAX; q += 256) lh[q] = 0;
  __syncthreads();
  for (int i = start + t; i < end; i += 256)
    atomicAdd(&lh[col[i] >> 7], 1);
  __syncthreads();
  for (int q = t; q < NBKMAX; q += 256){
    lbase[q] = (lh[q] > 0) ? atomicAdd(&bcur[q], lh[q]) : 0;
    lh[q] = 0;
  }
  __syncthreads();
  for (int i = start + t; i < end; i += 256){
    int c = col[i], r = row[i];
    int b = c >> 7;
    int p = atomicAdd(&lh[b], 1);
    bkt[(size_t)lbase[b] + p] = ((unsigned int)c << 16) | (unsigned int)r;
  }
}

__global__ void k_fill3(const unsigned int* __restrict__ bkt, const int* __restrict__ bkb,
                        const int* __restrict__ bcnt, int* __restrict__ offs,
                        int* __restrict__ srcs, int n, int nbk){
  __shared__ int lcnt[128];
  __shared__ int lex[128];
  __shared__ unsigned short ls[FMAX];
  int b = blockIdx.x;
  int t = threadIdx.x;
  int nlo = b << 7;
  int glo = bkb[b];
  int cb = bcnt[b];
  if (t < 128) lcnt[t] = 0;
  __syncthreads();
  for (int j = t; j < cb; j += 256)
    atomicAdd(&lcnt[(int)(bkt[(size_t)glo + j] >> 16) - nlo], 1);
  __syncthreads();
  if (t < 128) lex[t] = lcnt[t];
  __syncthreads();
  for (int d = 1; d < 128; d <<= 1){
    int a = (t >= d && t < 128) ? lex[t - d] : 0;
    __syncthreads();
    if (t < 128) lex[t] += a;
    __syncthreads();
  }
  if (t < 128){
    int node = nlo + t;
    int ex = lex[t] - lcnt[t];
    if (node < n) offs[node] = glo + ex;
    lcnt[t] = ex;                       // reuse as cursor
  }
  if (t == 0 && b == nbk - 1) offs[n] = glo + cb;
  __syncthreads();
  for (int j = t; j < cb; j += 256){
    unsigned int pk = bkt[(size_t)glo + j];
    int c = (int)(pk >> 16) - nlo;
    int p = atomicAdd(&lcnt[c], 1);
    if (p < FMAX) ls[p] = (unsigned short)(pk & 0xFFFFu);
  }
  __syncthreads();
  for (int j = t; j < cb; j += 256) srcs[glo + j] = (int)ls[j];
}

// ---------------- fallback CSR build for N >= 65536 ----------------
__global__ void k_hist(const int* __restrict__ col, int* __restrict__ cnt, int e){
  for (int i = blockIdx.x * blockDim.x + threadIdx.x; i < e; i += gridDim.x * blockDim.x)
    atomicAdd(&cnt[col[i]], 1);
}

__global__ void k_scan1(const int* __restrict__ cnt, int* __restrict__ loc,
                        int* __restrict__ btot, int n){
  __shared__ int sdata[1024];
  int t = threadIdx.x;
  int i = blockIdx.x * 1024 + t;
  int v = (i < n) ? cnt[i] : 0;
  sdata[t] = v;
  __syncthreads();
  for (int d = 1; d < 1024; d <<= 1){
    int a = (t >= d) ? sdata[t - d] : 0;
    __syncthreads();
    sdata[t] += a;
    __syncthreads();
  }
  if (i < n) loc[i] = sdata[t] - v;
  if (t == 1023) btot[blockIdx.x] = sdata[1023];
}

__global__ void k_scan2(const int* __restrict__ btot, int* __restrict__ bbase,
                        int nb, int* __restrict__ offs, int n){
  int lane = threadIdx.x & 63;
  int carry = 0;
  for (int s = 0; s < nb; s += 64){
    int idx = s + lane;
    int v = (idx < nb) ? btot[idx] : 0;
    int incl = v;
    #pragma unroll
    for (int d = 1; d < 64; d <<= 1){
      int o = __shfl_up(incl, d);
      if (lane >= d) incl += o;
    }
    if (idx < nb) bbase[idx] = carry + incl - v;
    carry += __shfl(incl, 63);
  }
  if (lane == 0) offs[n] = carry;
}

__global__ void k_scan3(const int* __restrict__ loc, const int* __restrict__ bbase,
                        int* __restrict__ offs, int* __restrict__ cur, int n){
  int i = blockIdx.x * blockDim.x + threadIdx.x;
  if (i < n){
    int ex = loc[i] + bbase[i >> 10];
    offs[i] = ex;
    cur[i] = ex;
  }
}

__global__ void k_fill(const int* __restrict__ row, const int* __restrict__ col,
                       int* __restrict__ cur, int* __restrict__ srcs, int e){
  for (int i = blockIdx.x * blockDim.x + threadIdx.x; i < e; i += gridDim.x * blockDim.x){
    int c = col[i];
    int p = atomicAdd(&cur[c], 1);
    srcs[p] = row[i];
  }
}

// ---------------- scatter_mean over bf16 rows: one node per 16-LANE GROUP ----------------
// FUSE=1 (hop 2): also computes logits (xb@U0 + c1@U1 + mean_fp32@U2 + lc), softmax -> att.
template <int FUSE>
__global__ void k_agg(const unsigned short* __restrict__ src, unsigned short* __restrict__ dst,
                      const int* __restrict__ offs, const int* __restrict__ srcs,
                      const unsigned short* __restrict__ xb, const float* __restrict__ U,
                      const float* __restrict__ lc, float* __restrict__ att, int n){
  int qg = (blockIdx.x * blockDim.x + threadIdx.x) >> 4;
  int lane = threadIdx.x & 15;
  int nqg = (gridDim.x * blockDim.x) >> 4;
  const u16x8* s8 = (const u16x8*)src;     // 16 x u16x8 per row
  for (int node = qg; node < n; node += nqg){
    int o0 = offs[node], o1 = offs[node + 1];
    float a0 = 0, a1 = 0, a2 = 0, a3 = 0, a4 = 0, a5 = 0, a6 = 0, a7 = 0;
    for (int base = o0; base < o1; base += 16){
      int m = o1 - base; if (m > 16) m = 16;
      int myidx = (base + lane < o1) ? srcs[base + lane] : 0;
      int j = 0;
      for (; j + 4 <= m; j += 4){
        int i0 = __shfl(myidx, j, 16);
        int i1 = __shfl(myidx, j + 1, 16);
        int i2 = __shfl(myidx, j + 2, 16);
        int i3 = __shfl(myidx, j + 3, 16);
        u16x8 v0 = s8[(size_t)i0 * 16 + lane];
        u16x8 v1 = s8[(size_t)i1 * 16 + lane];
        u16x8 v2 = s8[(size_t)i2 * 16 + lane];
        u16x8 v3 = s8[(size_t)i3 * 16 + lane];
        a0 += (b2f(v0[0]) + b2f(v1[0])) + (b2f(v2[0]) + b2f(v3[0]));
        a1 += (b2f(v0[1]) + b2f(v1[1])) + (b2f(v2[1]) + b2f(v3[1]));
        a2 += (b2f(v0[2]) + b2f(v1[2])) + (b2f(v2[2]) + b2f(v3[2]));
        a3 += (b2f(v0[3]) + b2f(v1[3])) + (b2f(v2[3]) + b2f(v3[3]));
        a4 += (b2f(v0[4]) + b2f(v1[4])) + (b2f(v2[4]) + b2f(v3[4]));
        a5 += (b2f(v0[5]) + b2f(v1[5])) + (b2f(v2[5]) + b2f(v3[5]));
        a6 += (b2f(v0[6]) + b2f(v1[6])) + (b2f(v2[6]) + b2f(v3[6]));
        a7 += (b2f(v0[7]) + b2f(v1[7])) + (b2f(v2[7]) + b2f(v3[7]));
      }
      for (; j < m; ++j){
        int s = __shfl(myidx, j, 16);
        u16x8 v = s8[(size_t)s * 16 + lane];
        a0 += b2f(v[0]); a1 += b2f(v[1]); a2 += b2f(v[2]); a3 += b2f(v[3]);
        a4 += b2f(v[4]); a5 += b2f(v[5]); a6 += b2f(v[6]); a7 += b2f(v[7]);
      }
    }
    float inv = 1.0f / fmaxf((float)(o1 - o0), 1.0f);
    float mm[8];
    mm[0] = a0 * inv; mm[1] = a1 * inv; mm[2] = a2 * inv; mm[3] = a3 * inv;
    mm[4] = a4 * inv; mm[5] = a5 * inv; mm[6] = a6 * inv; mm[7] = a7 * inv;
    u16x8 r;
    #pragma unroll
    for (int e = 0; e < 8; ++e) r[e] = f2b(mm[e]);
    ((u16x8*)dst)[(size_t)node * 16 + lane] = r;

    if (FUSE){
      u16x8 xv  = ((const u16x8*)xb)[(size_t)node * 16 + lane];
      u16x8 c1v = s8[(size_t)node * 16 + lane];   // src == c1b
      int kb = lane * 8;
      float l0 = 0, l1 = 0, l2 = 0;
      #pragma unroll
      for (int e = 0; e < 8; ++e){
        float x0 = b2f(xv[e]);
        float x1 = b2f(c1v[e]);
        float x2 = mm[e];
        int k = kb + e;
        l0 += x0 * U[0 * DD + k] + x1 * U[3 * DD + k] + x2 * U[6 * DD + k];
        l1 += x0 * U[1 * DD + k] + x1 * U[4 * DD + k] + x2 * U[7 * DD + k];
        l2 += x0 * U[2 * DD + k] + x1 * U[5 * DD + k] + x2 * U[8 * DD + k];
      }
      #pragma unroll
      for (int off = 8; off; off >>= 1){
        l0 += __shfl_xor(l0, off, 16);
        l1 += __shfl_xor(l1, off, 16);
        l2 += __shfl_xor(l2, off, 16);
      }
      if (lane == 0){
        l0 += lc[0]; l1 += lc[1]; l2 += lc[2];
        float mx = fmaxf(l0, fmaxf(l1, l2));
        float e0 = __expf(l0 - mx), e1 = __expf(l1 - mx), e2 = __expf(l2 - mx);
        float is = 1.0f / (e0 + e1 + e2);
        *(float4*)(att + (size_t)node * 4) = make_float4(e0 * is, e1 * is, e2 * is, 0.0f);
      }
    }
  }
}

// ---------------- fused output GEMM via MFMA (bf16), LDS-free ----------------
__global__ __launch_bounds__(256) void k_out(
    const unsigned short* __restrict__ xb, const unsigned short* __restrict__ c1b,
    const unsigned short* __restrict__ c2b,
    const float* __restrict__ att, const unsigned short* __restrict__ Vt,
    const float* __restrict__ ob, const float* __restrict__ bf,
    float* __restrict__ out, int n){
  int t = threadIdx.x;
  int w = t >> 6, l = t & 63;
  int ng = w & 1, ch = w >> 1;
  int mbase = blockIdx.x * 32 + ng * 16;
  int colbase = ch * 64;
  int lm = l & 15, lg = l >> 4;

  f32x4 acc[4][3];
  #pragma unroll
  for (int ct = 0; ct < 4; ++ct)
    #pragma unroll
    for (int i = 0; i < 3; ++i) acc[ct][i] = (f32x4){0.f, 0.f, 0.f, 0.f};

  int mrow = mbase + lm;
  if (mrow > n - 1) mrow = n - 1;      // clamped load row (discarded at store)

  #pragma unroll
  for (int kt = 0; kt < 12; ++kt){
    int i = kt >> 2;
    int kc0 = (kt & 3) << 5;
    const unsigned short* cb = (i == 0) ? xb : (i == 1) ? c1b : c2b;
    bf16x8 a = *(const bf16x8*)(cb + (size_t)mrow * DD + kc0 + lg * 8);
    #pragma unroll
    for (int ct = 0; ct < 4; ++ct){
      int ncol = colbase + ct * 16 + lm;
      bf16x8 b = *(const bf16x8*)(Vt + ((((size_t)kt * DD + ncol) * 4 + lg) << 3));
      acc[ct][i] = __builtin_amdgcn_mfma_f32_16x16x32_bf16(a, b, acc[ct][i], 0, 0, 0);
    }
  }

  #pragma unroll
  for (int j = 0; j < 4; ++j){
    int node = mbase + lg * 4 + j;
    if (node < n){
      float4 av = *(const float4*)(att + (size_t)node * 4);
      #pragma unroll
      for (int ct = 0; ct < 4; ++ct){
        int col = colbase + ct * 16 + lm;
        float r = acc[ct][0][j] * av.x + acc[ct][1][j] * av.y + acc[ct][2][j] * av.z
                + bf[col] + av.x * ob[0 * DD + col] + av.y * ob[1 * DD + col]
                + av.z * ob[2 * DD + col];
        out[(size_t)node * DD + col] = r;
      }
    }
  }
}

extern "C" void kernel_launch(void* const* d_in, const int* in_sizes, int n_in,
                              void* d_out, int out_size, void* d_ws, size_t ws_size,
                              hipStream_t stream){
  const float* x   = (const float*)d_in[0];
  const int*   ei  = (const int*)d_in[1];
  const int*   dep = (const int*)d_in[2];
  const float* Wh  = (const float*)d_in[3];
  const float* bh  = (const float*)d_in[4];
  const float* Wg1 = (const float*)d_in[5];
  const float* bg1 = (const float*)d_in[6];
  const float* Wg2 = (const float*)d_in[7];
  const float* bg2 = (const float*)d_in[8];
  const float* Wa  = (const float*)d_in[9];
  const float* ba  = (const float*)d_in[10];
  const float* Wf  = (const float*)d_in[11];
  const float* bf  = (const float*)d_in[12];
  float* out = (float*)d_out;

  int N = in_sizes[0] / DD;
  int E = in_sizes[1] / 2;
  if (N <= 0) return;
  const int* row = ei;
  const int* col = ei + E;

  char* w = (char*)d_ws;
  size_t o = 0;
  auto alloc = [&](size_t bytes) -> void* {
    void* p = w + o;
    o += (bytes + 255) & ~(size_t)255;
    return p;
  };
  unsigned short* xb  = (unsigned short*)alloc((size_t)N * DD * 2);
  unsigned short* c1b = (unsigned short*)alloc((size_t)N * DD * 2);
  unsigned short* c2b = (unsigned short*)alloc((size_t)N * DD * 2);
  float* att  = (float*)alloc((size_t)N * 4 * 4);
  unsigned short* Vt = (unsigned short*)alloc((size_t)3 * DD * DD * 2);
  float* ob   = (float*)alloc((size_t)3 * DD * 4);
  float* U    = (float*)alloc((size_t)9 * DD * 4);
  float* lc   = (float*)alloc(16);
  float* sw   = (float*)alloc(16);
  int*   maxd = (int*)alloc(16);
  int*   cnt  = (int*)alloc((size_t)N * 4);
  int*   offs = (int*)alloc((size_t)(N + 1) * 4);
  int*   cur  = (int*)alloc((size_t)N * 4);
  int*   srcs = (int*)alloc((size_t)E * 4);
  int*   loc  = (int*)alloc((size_t)N * 4);
  int    nb   = (N + 1023) / 1024;
  int*   btot = (int*)alloc((size_t)nb * 4);
  int*   bbase= (int*)alloc((size_t)nb * 4);
  int*   bcnt = (int*)alloc(NBKMAX * 4);
  int*   bkb  = (int*)alloc(NBKMAX * 4);
  int*   bcur = (int*)alloc(NBKMAX * 4);
  unsigned int* bkt = (unsigned int*)alloc((size_t)E * 4);

  hipMemsetAsync(maxd, 0, 4, stream);

  k_dc<<<1024, 256, 0, stream>>>(dep, maxd, x, xb, N, N * DD / 4);
  k_gate<<<1, 64, 0, stream>>>(maxd, Wg1, bg1, Wg2, bg2, ba, sw, lc, (float)N / 5000.0f);
  k_combine<<<dim3(129, 3), 128, 0, stream>>>(Wh, bh, Wf, sw, Vt, ob);
  k_ua<<<3, 128, 0, stream>>>(Wh, bh, Wa, sw, U, lc);
  if (N <= 65535){
    int nbk = (N + 127) / 128;
    hipMemsetAsync(bcnt, 0, NBKMAX * 4, stream);
    k_histb<<<256, 256, 0, stream>>>(col, bcnt, E);
    k_bscan<<<1, 64, 0, stream>>>(bcnt, bkb, bcur, nbk);
    k_part<<<(E + 8191) / 8192, 256, 0, stream>>>(row, col, bcur, bkt, E);
    k_fill3<<<nbk, 256, 0, stream>>>(bkt, bkb, bcnt, offs, srcs, N, nbk);
  } else {
    hipMemsetAsync(cnt, 0, (size_t)N * 4, stream);
    k_hist<<<(E + 255) / 256, 256, 0, stream>>>(col, cnt, E);
    k_scan1<<<nb, 1024, 0, stream>>>(cnt, loc, btot, N);
    k_scan2<<<1, 64, 0, stream>>>(btot, bbase, nb, offs, N);
    k_scan3<<<(N + 255) / 256, 256, 0, stream>>>(loc, bbase, offs, cur, N);
    k_fill<<<(E + 255) / 256, 256, 0, stream>>>(row, col, cur, srcs, E);
  }
  int aggBlocks = (N + 15) / 16;        // one node per 16-lane group
  k_agg<0><<<aggBlocks, 256, 0, stream>>>(xb, c1b, offs, srcs, nullptr, nullptr, nullptr, nullptr, N);
  k_agg<1><<<aggBlocks, 256, 0, stream>>>(c1b, c2b, offs, srcs, xb, U, lc, att, N);
  k_out<<<(N + 31) / 32, 256, 0, stream>>>(xb, c1b, c2b, att, Vt, ob, bf, out, N);
}

// Round 20
// 187.073 us; speedup vs baseline: 1.1953x; 1.1953x over previous
//
#include <hip/hip_runtime.h>
#include <hip/hip_bf16.h>

#define DD 128
#define NBKMAX 512
#define FMAX 4096

typedef __attribute__((ext_vector_type(8))) short bf16x8;
typedef __attribute__((ext_vector_type(8))) unsigned short u16x8;
typedef __attribute__((ext_vector_type(4))) float f32x4;

__device__ __forceinline__ float b2f(unsigned short u){
  return __uint_as_float((unsigned int)u << 16);
}
__device__ __forceinline__ unsigned short f2b(float f){
  unsigned int u = __float_as_uint(f);
  unsigned int r = (u + 0x7FFFu + ((u >> 16) & 1u)) >> 16;   // RNE
  return (unsigned short)r;
}

// ---------------- max depth reduction (128 blocks -> only 512 contended atomics) ----------------
__global__ void k_depthmax(const int* __restrict__ depths, int* __restrict__ maxd, int n){
  int v = 0;
  for (int i = blockIdx.x * blockDim.x + threadIdx.x; i < n; i += gridDim.x * blockDim.x){
    int d = depths[i]; v = d > v ? d : v;
  }
  #pragma unroll
  for (int off = 32; off; off >>= 1){ int o = __shfl_xor(v, off); v = o > v ? o : v; }
  if ((threadIdx.x & 63) == 0) atomicMax(maxd, v);
}

// ---------------- cast x -> bf16 shadow ----------------
__global__ void k_cast(const float* __restrict__ x, unsigned short* __restrict__ xb, int total4){
  int i = blockIdx.x * blockDim.x + threadIdx.x;
  if (i < total4){
    float4 v = ((const float4*)x)[i];
    ushort4 w;
    w.x = f2b(v.x); w.y = f2b(v.y); w.z = f2b(v.z); w.w = f2b(v.w);
    ((ushort4*)xb)[i] = w;
  }
}

// ---------------- gate MLP: scale_weights (sw[3]), init lc = ba ----------------
__global__ void k_gate(const int* __restrict__ maxd, const float* __restrict__ Wg1,
                       const float* __restrict__ bg1, const float* __restrict__ Wg2,
                       const float* __restrict__ bg2, const float* __restrict__ ba,
                       float* __restrict__ sw, float* __restrict__ lc, float sf0){
  __shared__ float h[32];
  int t = threadIdx.x;
  float sf1 = (float)(*maxd) / 20.0f;
  if (t < 32) h[t] = fmaxf(0.0f, sf0 * Wg1[t] + sf1 * Wg1[32 + t] + bg1[t]);
  __syncthreads();
  if (t < 3){
    float s = bg2[t];
    for (int k = 0; k < 32; ++k) s += h[k] * Wg2[k * 3 + t];
    sw[t] = 1.0f / (1.0f + __expf(-s));
    lc[t] = ba[t];
  }
}

// ---------------- combined matrices: Vt (bf16, B-fragment order) and ob ----------------
__global__ void k_combine(const float* __restrict__ Wh, const float* __restrict__ bh,
                          const float* __restrict__ Wf, const float* __restrict__ sw,
                          unsigned short* __restrict__ Vt, float* __restrict__ ob){
  int k = blockIdx.x;        // 0..128 (128 == bias row)
  int i = blockIdx.y;        // hop
  int c = threadIdx.x;       // col 0..127
  float s = sw[i];
  float acc = 0.0f;
  if (k < DD){
    for (int d = 0; d < DD; ++d)
      acc += Wh[(i * DD + k) * DD + d] * Wf[(i * DD + d) * DD + c];
    int ktt = i * 4 + (k >> 5);
    int g = (k >> 3) & 3;
    int j = k & 7;
    Vt[((((size_t)ktt * DD + c) * 4 + g) << 3) + j] = f2b(s * acc);
  } else {
    for (int d = 0; d < DD; ++d)
      acc += bh[i * DD + d] * Wf[(i * DD + d) * DD + c];
    ob[i * DD + c] = s * acc;
  }
}

// ---------------- U (transposed): U[(i*3+j)*DD + k]; lc += sw_i * bh_i @ Wa_i ----------------
__global__ void k_ua(const float* __restrict__ Wh, const float* __restrict__ bh,
                     const float* __restrict__ Wa, const float* __restrict__ sw,
                     float* __restrict__ U, float* __restrict__ lc){
  int i = blockIdx.x, k = threadIdx.x;
  float s = sw[i];
  float a0 = 0, a1 = 0, a2 = 0;
  for (int d = 0; d < DD; ++d){
    float w = Wh[(i * DD + k) * DD + d];
    a0 += w * Wa[(i * DD + d) * 3 + 0];
    a1 += w * Wa[(i * DD + d) * 3 + 1];
    a2 += w * Wa[(i * DD + d) * 3 + 2];
  }
  U[(i * 3 + 0) * DD + k] = s * a0;
  U[(i * 3 + 1) * DD + k] = s * a1;
  U[(i * 3 + 2) * DD + k] = s * a2;
  if (k < 3){
    float b = 0;
    for (int d = 0; d < DD; ++d) b += bh[i * DD + d] * Wa[(i * DD + d) * 3 + k];
    atomicAdd(&lc[k], s * b);
  }
}

// ---------------- CSR build (fast path, N<65536): bucket histogram only ----------------
__global__ void k_histb(const int* __restrict__ col, int* __restrict__ bcnt, int e){
  __shared__ int lb[NBKMAX];
  int t = threadIdx.x;
  for (int q = t; q < NBKMAX; q += 256) lb[q] = 0;
  __syncthreads();
  for (int i = blockIdx.x * blockDim.x + t; i < e; i += gridDim.x * blockDim.x)
    atomicAdd(&lb[col[i] >> 7], 1);
  __syncthreads();
  for (int q = t; q < NBKMAX; q += 256)
    if (lb[q] > 0) atomicAdd(&bcnt[q], lb[q]);
}

__global__ void k_bscan(const int* __restrict__ bcnt, int* __restrict__ bkb,
                        int* __restrict__ bcur, int nbk){
  int lane = threadIdx.x & 63;
  int carry = 0;
  for (int s = 0; s < nbk; s += 64){
    int idx = s + lane;
    int v = (idx < nbk) ? bcnt[idx] : 0;
    int incl = v;
    #pragma unroll
    for (int d = 1; d < 64; d <<= 1){
      int o = __shfl_up(incl, d);
      if (lane >= d) incl += o;
    }
    if (idx < nbk){ int ex = carry + incl - v; bkb[idx] = ex; bcur[idx] = ex; }
    carry += __shfl(incl, 63);
  }
}

__global__ void k_part(const int* __restrict__ row, const int* __restrict__ col,
                       int* __restrict__ bcur, unsigned int* __restrict__ bkt, int e){
  __shared__ int lh[NBKMAX];
  __shared__ int lbase[NBKMAX];
  int t = threadIdx.x;
  int start = blockIdx.x * 8192;
  int end = start + 8192; if (end > e) end = e;
  for (int q = t; q < NBKMAX; q += 256) lh[q] = 0;
  __syncthreads();
  for (int i = start + t; i < end; i += 256)
    atomicAdd(&lh[col[i] >> 7], 1);
  __syncthreads();
  for (int q = t; q < NBKMAX; q += 256){
    lbase[q] = (lh[q] > 0) ? atomicAdd(&bcur[q], lh[q]) : 0;
    lh[q] = 0;
  }
  __syncthreads();
  for (int i = start + t; i < end; i += 256){
    int c = col[i], r = row[i];
    int b = c >> 7;
    int p = atomicAdd(&lh[b], 1);
    bkt[(size_t)lbase[b] + p] = ((unsigned int)c << 16) | (unsigned int)r;
  }
}

__global__ void k_fill3(const unsigned int* __restrict__ bkt, const int* __restrict__ bkb,
                        const int* __restrict__ bcnt, int* __restrict__ offs,
                        int* __restrict__ srcs, int n, int nbk){
  __shared__ int lcnt[128];
  __shared__ int lex[128];
  __shared__ unsigned short ls[FMAX];
  int b = blockIdx.x;
  int t = threadIdx.x;
  int nlo = b << 7;
  int glo = bkb[b];
  int cb = bcnt[b];
  if (t < 128) lcnt[t] = 0;
  __syncthreads();
  for (int j = t; j < cb; j += 256)
    atomicAdd(&lcnt[(int)(bkt[(size_t)glo + j] >> 16) - nlo], 1);
  __syncthreads();
  if (t < 128) lex[t] = lcnt[t];
  __syncthreads();
  for (int d = 1; d < 128; d <<= 1){
    int a = (t >= d && t < 128) ? lex[t - d] : 0;
    __syncthreads();
    if (t < 128) lex[t] += a;
    __syncthreads();
  }
  if (t < 128){
    int node = nlo + t;
    int ex = lex[t] - lcnt[t];
    if (node < n) offs[node] = glo + ex;
    lcnt[t] = ex;                       // reuse as cursor
  }
  if (t == 0 && b == nbk - 1) offs[n] = glo + cb;
  __syncthreads();
  for (int j = t; j < cb; j += 256){
    unsigned int pk = bkt[(size_t)glo + j];
    int c = (int)(pk >> 16) - nlo;
    int p = atomicAdd(&lcnt[c], 1);
    if (p < FMAX) ls[p] = (unsigned short)(pk & 0xFFFFu);
  }
  __syncthreads();
  for (int j = t; j < cb; j += 256) srcs[glo + j] = (int)ls[j];
}

// ---------------- fallback CSR build for N >= 65536 ----------------
__global__ void k_hist(const int* __restrict__ col, int* __restrict__ cnt, int e){
  for (int i = blockIdx.x * blockDim.x + threadIdx.x; i < e; i += gridDim.x * blockDim.x)
    atomicAdd(&cnt[col[i]], 1);
}

__global__ void k_scan1(const int* __restrict__ cnt, int* __restrict__ loc,
                        int* __restrict__ btot, int n){
  __shared__ int sdata[1024];
  int t = threadIdx.x;
  int i = blockIdx.x * 1024 + t;
  int v = (i < n) ? cnt[i] : 0;
  sdata[t] = v;
  __syncthreads();
  for (int d = 1; d < 1024; d <<= 1){
    int a = (t >= d) ? sdata[t - d] : 0;
    __syncthreads();
    sdata[t] += a;
    __syncthreads();
  }
  if (i < n) loc[i] = sdata[t] - v;
  if (t == 1023) btot[blockIdx.x] = sdata[1023];
}

__global__ void k_scan2(const int* __restrict__ btot, int* __restrict__ bbase,
                        int nb, int* __restrict__ offs, int n){
  int lane = threadIdx.x & 63;
  int carry = 0;
  for (int s = 0; s < nb; s += 64){
    int idx = s + lane;
    int v = (idx < nb) ? btot[idx] : 0;
    int incl = v;
    #pragma unroll
    for (int d = 1; d < 64; d <<= 1){
      int o = __shfl_up(incl, d);
      if (lane >= d) incl += o;
    }
    if (idx < nb) bbase[idx] = carry + incl - v;
    carry += __shfl(incl, 63);
  }
  if (lane == 0) offs[n] = carry;
}

__global__ void k_scan3(const int* __restrict__ loc, const int* __restrict__ bbase,
                        int* __restrict__ offs, int* __restrict__ cur, int n){
  int i = blockIdx.x * blockDim.x + threadIdx.x;
  if (i < n){
    int ex = loc[i] + bbase[i >> 10];
    offs[i] = ex;
    cur[i] = ex;
  }
}

__global__ void k_fill(const int* __restrict__ row, const int* __restrict__ col,
                       int* __restrict__ cur, int* __restrict__ srcs, int e){
  for (int i = blockIdx.x * blockDim.x + threadIdx.x; i < e; i += gridDim.x * blockDim.x){
    int c = col[i];
    int p = atomicAdd(&cur[c], 1);
    srcs[p] = row[i];
  }
}

// ---------------- scatter_mean over bf16 rows: one node per 16-LANE GROUP ----------------
// FUSE=1 (hop 2): also computes logits (xb@U0 + c1@U1 + mean_fp32@U2 + lc), softmax -> att.
template <int FUSE>
__global__ void k_agg(const unsigned short* __restrict__ src, unsigned short* __restrict__ dst,
                      const int* __restrict__ offs, const int* __restrict__ srcs,
                      const unsigned short* __restrict__ xb, const float* __restrict__ U,
                      const float* __restrict__ lc, float* __restrict__ att, int n){
  int qg = (blockIdx.x * blockDim.x + threadIdx.x) >> 4;
  int lane = threadIdx.x & 15;
  int nqg = (gridDim.x * blockDim.x) >> 4;
  const u16x8* s8 = (const u16x8*)src;     // 16 x u16x8 per row
  for (int node = qg; node < n; node += nqg){
    int o0 = offs[node], o1 = offs[node + 1];
    float a0 = 0, a1 = 0, a2 = 0, a3 = 0, a4 = 0, a5 = 0, a6 = 0, a7 = 0;
    for (int base = o0; base < o1; base += 16){
      int m = o1 - base; if (m > 16) m = 16;
      int myidx = (base + lane < o1) ? srcs[base + lane] : 0;
      int j = 0;
      for (; j + 4 <= m; j += 4){
        int i0 = __shfl(myidx, j, 16);
        int i1 = __shfl(myidx, j + 1, 16);
        int i2 = __shfl(myidx, j + 2, 16);
        int i3 = __shfl(myidx, j + 3, 16);
        u16x8 v0 = s8[(size_t)i0 * 16 + lane];
        u16x8 v1 = s8[(size_t)i1 * 16 + lane];
        u16x8 v2 = s8[(size_t)i2 * 16 + lane];
        u16x8 v3 = s8[(size_t)i3 * 16 + lane];
        a0 += (b2f(v0[0]) + b2f(v1[0])) + (b2f(v2[0]) + b2f(v3[0]));
        a1 += (b2f(v0[1]) + b2f(v1[1])) + (b2f(v2[1]) + b2f(v3[1]));
        a2 += (b2f(v0[2]) + b2f(v1[2])) + (b2f(v2[2]) + b2f(v3[2]));
        a3 += (b2f(v0[3]) + b2f(v1[3])) + (b2f(v2[3]) + b2f(v3[3]));
        a4 += (b2f(v0[4]) + b2f(v1[4])) + (b2f(v2[4]) + b2f(v3[4]));
        a5 += (b2f(v0[5]) + b2f(v1[5])) + (b2f(v2[5]) + b2f(v3[5]));
        a6 += (b2f(v0[6]) + b2f(v1[6])) + (b2f(v2[6]) + b2f(v3[6]));
        a7 += (b2f(v0[7]) + b2f(v1[7])) + (b2f(v2[7]) + b2f(v3[7]));
      }
      for (; j < m; ++j){
        int s = __shfl(myidx, j, 16);
        u16x8 v = s8[(size_t)s * 16 + lane];
        a0 += b2f(v[0]); a1 += b2f(v[1]); a2 += b2f(v[2]); a3 += b2f(v[3]);
        a4 += b2f(v[4]); a5 += b2f(v[5]); a6 += b2f(v[6]); a7 += b2f(v[7]);
      }
    }
    float inv = 1.0f / fmaxf((float)(o1 - o0), 1.0f);
    float mm[8];
    mm[0] = a0 * inv; mm[1] = a1 * inv; mm[2] = a2 * inv; mm[3] = a3 * inv;
    mm[4] = a4 * inv; mm[5] = a5 * inv; mm[6] = a6 * inv; mm[7] = a7 * inv;
    u16x8 r;
    #pragma unroll
    for (int e = 0; e < 8; ++e) r[e] = f2b(mm[e]);
    ((u16x8*)dst)[(size_t)node * 16 + lane] = r;

    if (FUSE){
      u16x8 xv  = ((const u16x8*)xb)[(size_t)node * 16 + lane];
      u16x8 c1v = s8[(size_t)node * 16 + lane];   // src == c1b
      int kb = lane * 8;
      float l0 = 0, l1 = 0, l2 = 0;
      #pragma unroll
      for (int e = 0; e < 8; ++e){
        float x0 = b2f(xv[e]);
        float x1 = b2f(c1v[e]);
        float x2 = mm[e];
        int k = kb + e;
        l0 += x0 * U[0 * DD + k] + x1 * U[3 * DD + k] + x2 * U[6 * DD + k];
        l1 += x0 * U[1 * DD + k] + x1 * U[4 * DD + k] + x2 * U[7 * DD + k];
        l2 += x0 * U[2 * DD + k] + x1 * U[5 * DD + k] + x2 * U[8 * DD + k];
      }
      #pragma unroll
      for (int off = 8; off; off >>= 1){
        l0 += __shfl_xor(l0, off, 16);
        l1 += __shfl_xor(l1, off, 16);
        l2 += __shfl_xor(l2, off, 16);
      }
      if (lane == 0){
        l0 += lc[0]; l1 += lc[1]; l2 += lc[2];
        float mx = fmaxf(l0, fmaxf(l1, l2));
        float e0 = __expf(l0 - mx), e1 = __expf(l1 - mx), e2 = __expf(l2 - mx);
        float is = 1.0f / (e0 + e1 + e2);
        *(float4*)(att + (size_t)node * 4) = make_float4(e0 * is, e1 * is, e2 * is, 0.0f);
      }
    }
  }
}

// ---------------- fused output GEMM via MFMA (bf16), LDS-free ----------------
__global__ __launch_bounds__(256) void k_out(
    const unsigned short* __restrict__ xb, const unsigned short* __restrict__ c1b,
    const unsigned short* __restrict__ c2b,
    const float* __restrict__ att, const unsigned short* __restrict__ Vt,
    const float* __restrict__ ob, const float* __restrict__ bf,
    float* __restrict__ out, int n){
  int t = threadIdx.x;
  int w = t >> 6, l = t & 63;
  int ng = w & 1, ch = w >> 1;
  int mbase = blockIdx.x * 32 + ng * 16;
  int colbase = ch * 64;
  int lm = l & 15, lg = l >> 4;

  f32x4 acc[4][3];
  #pragma unroll
  for (int ct = 0; ct < 4; ++ct)
    #pragma unroll
    for (int i = 0; i < 3; ++i) acc[ct][i] = (f32x4){0.f, 0.f, 0.f, 0.f};

  int mrow = mbase + lm;
  if (mrow > n - 1) mrow = n - 1;      // clamped load row (discarded at store)

  #pragma unroll
  for (int kt = 0; kt < 12; ++kt){
    int i = kt >> 2;
    int kc0 = (kt & 3) << 5;
    const unsigned short* cb = (i == 0) ? xb : (i == 1) ? c1b : c2b;
    bf16x8 a = *(const bf16x8*)(cb + (size_t)mrow * DD + kc0 + lg * 8);
    #pragma unroll
    for (int ct = 0; ct < 4; ++ct){
      int ncol = colbase + ct * 16 + lm;
      bf16x8 b = *(const bf16x8*)(Vt + ((((size_t)kt * DD + ncol) * 4 + lg) << 3));
      acc[ct][i] = __builtin_amdgcn_mfma_f32_16x16x32_bf16(a, b, acc[ct][i], 0, 0, 0);
    }
  }

  #pragma unroll
  for (int j = 0; j < 4; ++j){
    int node = mbase + lg * 4 + j;
    if (node < n){
      float4 av = *(const float4*)(att + (size_t)node * 4);
      #pragma unroll
      for (int ct = 0; ct < 4; ++ct){
        int col = colbase + ct * 16 + lm;
        float r = acc[ct][0][j] * av.x + acc[ct][1][j] * av.y + acc[ct][2][j] * av.z
                + bf[col] + av.x * ob[0 * DD + col] + av.y * ob[1 * DD + col]
                + av.z * ob[2 * DD + col];
        out[(size_t)node * DD + col] = r;
      }
    }
  }
}

extern "C" void kernel_launch(void* const* d_in, const int* in_sizes, int n_in,
                              void* d_out, int out_size, void* d_ws, size_t ws_size,
                              hipStream_t stream){
  const float* x   = (const float*)d_in[0];
  const int*   ei  = (const int*)d_in[1];
  const int*   dep = (const int*)d_in[2];
  const float* Wh  = (const float*)d_in[3];
  const float* bh  = (const float*)d_in[4];
  const float* Wg1 = (const float*)d_in[5];
  const float* bg1 = (const float*)d_in[6];
  const float* Wg2 = (const float*)d_in[7];
  const float* bg2 = (const float*)d_in[8];
  const float* Wa  = (const float*)d_in[9];
  const float* ba  = (const float*)d_in[10];
  const float* Wf  = (const float*)d_in[11];
  const float* bf  = (const float*)d_in[12];
  float* out = (float*)d_out;

  int N = in_sizes[0] / DD;
  int E = in_sizes[1] / 2;
  if (N <= 0) return;
  const int* row = ei;
  const int* col = ei + E;

  char* w = (char*)d_ws;
  size_t o = 0;
  auto alloc = [&](size_t bytes) -> void* {
    void* p = w + o;
    o += (bytes + 255) & ~(size_t)255;
    return p;
  };
  unsigned short* xb  = (unsigned short*)alloc((size_t)N * DD * 2);
  unsigned short* c1b = (unsigned short*)alloc((size_t)N * DD * 2);
  unsigned short* c2b = (unsigned short*)alloc((size_t)N * DD * 2);
  float* att  = (float*)alloc((size_t)N * 4 * 4);
  unsigned short* Vt = (unsigned short*)alloc((size_t)3 * DD * DD * 2);
  float* ob   = (float*)alloc((size_t)3 * DD * 4);
  float* U    = (float*)alloc((size_t)9 * DD * 4);
  float* lc   = (float*)alloc(16);
  float* sw   = (float*)alloc(16);
  int*   maxd = (int*)alloc(16);
  int*   cnt  = (int*)alloc((size_t)N * 4);
  int*   offs = (int*)alloc((size_t)(N + 1) * 4);
  int*   cur  = (int*)alloc((size_t)N * 4);
  int*   srcs = (int*)alloc((size_t)E * 4);
  int*   loc  = (int*)alloc((size_t)N * 4);
  int    nb   = (N + 1023) / 1024;
  int*   btot = (int*)alloc((size_t)nb * 4);
  int*   bbase= (int*)alloc((size_t)nb * 4);
  int*   bcnt = (int*)alloc(NBKMAX * 4);
  int*   bkb  = (int*)alloc(NBKMAX * 4);
  int*   bcur = (int*)alloc(NBKMAX * 4);
  unsigned int* bkt = (unsigned int*)alloc((size_t)E * 4);

  hipMemsetAsync(maxd, 0, 4, stream);

  k_depthmax<<<128, 256, 0, stream>>>(dep, maxd, N);
  k_cast<<<(N * DD / 4 + 255) / 256, 256, 0, stream>>>(x, xb, N * DD / 4);
  k_gate<<<1, 64, 0, stream>>>(maxd, Wg1, bg1, Wg2, bg2, ba, sw, lc, (float)N / 5000.0f);
  k_combine<<<dim3(129, 3), 128, 0, stream>>>(Wh, bh, Wf, sw, Vt, ob);
  k_ua<<<3, 128, 0, stream>>>(Wh, bh, Wa, sw, U, lc);
  if (N <= 65535){
    int nbk = (N + 127) / 128;
    hipMemsetAsync(bcnt, 0, NBKMAX * 4, stream);
    k_histb<<<256, 256, 0, stream>>>(col, bcnt, E);
    k_bscan<<<1, 64, 0, stream>>>(bcnt, bkb, bcur, nbk);
    k_part<<<(E + 8191) / 8192, 256, 0, stream>>>(row, col, bcur, bkt, E);
    k_fill3<<<nbk, 256, 0, stream>>>(bkt, bkb, bcnt, offs, srcs, N, nbk);
  } else {
    hipMemsetAsync(cnt, 0, (size_t)N * 4, stream);
    k_hist<<<(E + 255) / 256, 256, 0, stream>>>(col, cnt, E);
    k_scan1<<<nb, 1024, 0, stream>>>(cnt, loc, btot, N);
    k_scan2<<<1, 64, 0, stream>>>(btot, bbase, nb, offs, N);
    k_scan3<<<(N + 255) / 256, 256, 0, stream>>>(loc, bbase, offs, cur, N);
    k_fill<<<(E + 255) / 256, 256, 0, stream>>>(row, col, cur, srcs, E);
  }
  int aggBlocks = (N + 15) / 16;        // one node per 16-lane group
  k_agg<0><<<aggBlocks, 256, 0, stream>>>(xb, c1b, offs, srcs, nullptr, nullptr, nullptr, nullptr, N);
  k_agg<1><<<aggBlocks, 256, 0, stream>>>(c1b, c2b, offs, srcs, xb, U, lc, att, N);
  k_out<<<(N + 31) / 32, 256, 0, stream>>>(xb, c1b, c2b, att, Vt, ob, bf, out, N);
}